// Round 1
// baseline (304.299 us; speedup 1.0000x reference)
//
#include <hip/hip_runtime.h>

// Problem: N=1048576 nodes, D=256 feats, G=2048 graphs, batch sorted.
// Out = [graph_embedding (G*D f32), attention_scores (N f32)].
//
// Single-pass fused kernel: one block per graph, thread t owns feature t.
// Running (max, argmax, tie) per feature -> no second full read of x.

constexpr int DIM = 256;
constexpr float NEG_CLAMP = -3.4e38f;

__device__ __forceinline__ int lower_bound_i32(const int* __restrict__ a, int n, int v) {
    int lo = 0, hi = n;
    while (lo < hi) {
        int mid = (lo + hi) >> 1;
        if (a[mid] < v) lo = mid + 1; else hi = mid;
    }
    return lo;
}

__global__ __launch_bounds__(256, 4)
void segpool_kernel(const float* __restrict__ x,
                    const int* __restrict__ batch,
                    float* __restrict__ emb,     // [G, DIM]
                    float* __restrict__ scores,  // [N]
                    int N)
{
    const int g = blockIdx.x;
    const int t = threadIdx.x;

    // segment bounds (uniform across block; broadcast loads)
    const int start = lower_bound_i32(batch, N, g);
    const int end   = lower_bound_i32(batch, N, g + 1);

    // ---- Phase 1: streaming running max + argmax + tie flag for feature t ----
    float m  = -__builtin_huge_valf();
    int   am = -1;
    bool  tie = false;

    const float* __restrict__ col = x + t;

#define UPD(v, idx) do {                       \
        bool _gt = (v) > m;                    \
        tie = tie || ((v) == m);               \
        am = _gt ? (idx) : am;                 \
        m  = _gt ? (v) : m;                    \
    } while (0)

    int i = start;
    for (; i + 4 <= end; i += 4) {
        // 4 independent coalesced loads in flight (1 KB/row per block)
        float v0 = col[(size_t)(i + 0) * DIM];
        float v1 = col[(size_t)(i + 1) * DIM];
        float v2 = col[(size_t)(i + 2) * DIM];
        float v3 = col[(size_t)(i + 3) * DIM];
        UPD(v0, i + 0);
        UPD(v1, i + 1);
        UPD(v2, i + 2);
        UPD(v3, i + 3);
    }
    for (; i < end; ++i) {
        float v = col[(size_t)i * DIM];
        UPD(v, i);
    }
#undef UPD

    // graph embedding (empty segment -> -inf -> clamped to -3.4e38)
    emb[(size_t)g * DIM + t] = fmaxf(m, NEG_CLAMP);

    // ---- Phase 2: mark matches as 0/1 floats directly in scores ----
    for (int j = start + t; j < end; j += DIM) scores[j] = 0.0f;
    __syncthreads();   // zeros visible block-wide before scatter

    if (end > start) scores[am] = 1.0f;  // duplicate same-value stores are fine
    if (tie) {
        // rare: exact duplicate of the running max was seen; re-scan this
        // feature column and mark every exact hit of the FINAL max.
        for (int j = start; j < end; ++j) {
            float v = col[(size_t)j * DIM];
            if (v == m) scores[j] = 1.0f;
        }
    }
    __syncthreads();   // all 1-writes visible before counting

    // ---- Phase 3: count matches, then scale in place ----
    float cnt = 0.0f;
    for (int j = start + t; j < end; j += DIM) cnt += scores[j];

    // wave (64-lane) reduce, then combine 4 waves via LDS
    for (int off = 32; off > 0; off >>= 1) cnt += __shfl_down(cnt, off, 64);
    __shared__ float sred[4];
    const int wave = t >> 6;
    const int lane = t & 63;
    if (lane == 0) sred[wave] = cnt;
    __syncthreads();
    const float total = sred[0] + sred[1] + sred[2] + sred[3];
    const float inv = 1.0f / fmaxf(total, 1.0f);   // bit-exact: match/safe_sum with match in {0,1}

    for (int j = start + t; j < end; j += DIM) scores[j] *= inv;
}

extern "C" void kernel_launch(void* const* d_in, const int* in_sizes, int n_in,
                              void* d_out, int out_size, void* d_ws, size_t ws_size,
                              hipStream_t stream) {
    const float* x     = (const float*)d_in[0];
    const int*   batch = (const int*)d_in[1];
    // d_in[2] = num_graphs scalar (unused; derived from sizes below)

    const int N  = in_sizes[1];          // 1048576
    const int Dd = in_sizes[0] / N;      // 256
    const int G  = (out_size - N) / Dd;  // 2048

    float* emb    = (float*)d_out;
    float* scores = (float*)d_out + (size_t)G * Dd;

    segpool_kernel<<<G, 256, 0, stream>>>(x, batch, emb, scores, N);
}

// Round 2
// 294.594 us; speedup vs baseline: 1.0329x; 1.0329x over previous
//
#include <hip/hip_runtime.h>

// N=1048576 nodes, D=256 feats, G=2048 graphs, batch sorted.
// Out = [graph_embedding (G*256 f32), attention_scores (N f32)].
//
// One block per graph. float4 loads: lane l owns columns 4l..4l+3, one wave
// covers a full 1KB row per load instruction. Wave w streams rows
// start+w, start+w+4, ... keeping per-column running (max, argmax, tiebit).
// Cross-wave combine via LDS, then mark/count/scale scores in the (L2-hot)
// per-graph 2KB region.

constexpr int DIM = 256;
constexpr float NEG_CLAMP = -3.4e38f;

__device__ __forceinline__ int lower_bound_i32(const int* __restrict__ a, int n, int v) {
    int lo = 0, hi = n;
    while (lo < hi) {
        int mid = (lo + hi) >> 1;
        if (a[mid] < v) lo = mid + 1; else hi = mid;
    }
    return lo;
}

__global__ __launch_bounds__(256, 8)
void segpool_kernel(const float* __restrict__ x,
                    const int* __restrict__ batch,
                    float* __restrict__ emb,     // [G, DIM]
                    float* __restrict__ scores,  // [N]
                    int N)
{
    const int g = blockIdx.x;
    const int t = threadIdx.x;
    const int w = t >> 6;   // wave 0..3
    const int l = t & 63;   // lane

    const int start = lower_bound_i32(batch, N, g);
    const int end   = lower_bound_i32(batch, N, g + 1);

    // per-lane running state for columns 4l..4l+3 (this wave's row subset)
    float m0 = -__builtin_huge_valf(), m1 = m0, m2 = m0, m3 = m0;
    int   a0 = -1, a1 = -1, a2 = -1, a3 = -1;
    int   tieb = 0;

    const float4* __restrict__ xv = (const float4*)x;  // row i, lane l -> xv[i*64 + l]

#define UPD4(v, idx) do {                                             \
        bool g0 = (v).x > m0, g1 = (v).y > m1,                        \
             g2 = (v).z > m2, g3 = (v).w > m3;                        \
        tieb |= ((v).x == m0) ? 1 : 0;                                \
        tieb |= ((v).y == m1) ? 2 : 0;                                \
        tieb |= ((v).z == m2) ? 4 : 0;                                \
        tieb |= ((v).w == m3) ? 8 : 0;                                \
        a0 = g0 ? (idx) : a0;  m0 = g0 ? (v).x : m0;                  \
        a1 = g1 ? (idx) : a1;  m1 = g1 ? (v).y : m1;                  \
        a2 = g2 ? (idx) : a2;  m2 = g2 ? (v).z : m2;                  \
        a3 = g3 ? (idx) : a3;  m3 = g3 ? (v).w : m3;                  \
    } while (0)

    int i = start + w;
    for (; i + 4 < end; i += 8) {
        float4 va = xv[(size_t)i * 64 + l];
        float4 vb = xv[(size_t)(i + 4) * 64 + l];
        UPD4(va, i);
        UPD4(vb, i + 4);
    }
    for (; i < end; i += 4) {
        float4 va = xv[(size_t)i * 64 + l];
        UPD4(va, i);
    }
#undef UPD4

    // publish per-wave partials
    __shared__ float         sm[4][DIM];
    __shared__ int           sam[4][DIM];
    __shared__ unsigned char stie[4][DIM];
    const int c = l * 4;
    sm[w][c + 0] = m0;  sam[w][c + 0] = a0;  stie[w][c + 0] = (tieb >> 0) & 1;
    sm[w][c + 1] = m1;  sam[w][c + 1] = a1;  stie[w][c + 1] = (tieb >> 1) & 1;
    sm[w][c + 2] = m2;  sam[w][c + 2] = a2;  stie[w][c + 2] = (tieb >> 2) & 1;
    sm[w][c + 3] = m3;  sam[w][c + 3] = a3;  stie[w][c + 3] = (tieb >> 3) & 1;

    // zero this graph's scores region while partials land
    for (int j = start + t; j < end; j += DIM) scores[j] = 0.0f;
    __syncthreads();

    // combine 4 wave-partials for column t; mark matches
    const float M = fmaxf(fmaxf(sm[0][t], sm[1][t]), fmaxf(sm[2][t], sm[3][t]));
    emb[(size_t)g * DIM + t] = fmaxf(M, NEG_CLAMP);

    bool rescan = false;
    #pragma unroll
    for (int ww = 0; ww < 4; ++ww) {
        if (sm[ww][t] == M && sam[ww][t] >= 0) {
            scores[sam[ww][t]] = 1.0f;           // duplicate 1.0 stores benign
            rescan = rescan || (stie[ww][t] != 0);
        }
    }
    if (rescan) {
        // rare: an exact duplicate of a running max was seen in some wave that
        // attains the final max; re-scan column t and mark every exact hit.
        const float* __restrict__ col = x + t;
        for (int j = start; j < end; ++j)
            if (col[(size_t)j * DIM] == M) scores[j] = 1.0f;
    }
    __syncthreads();   // all 1-writes visible before counting

    // count matches (per-graph region is L2/L1 hot), then scale in place
    float cnt = 0.0f;
    for (int j = start + t; j < end; j += DIM) cnt += scores[j];
    for (int off = 32; off > 0; off >>= 1) cnt += __shfl_down(cnt, off, 64);

    __shared__ float sred[4];
    if (l == 0) sred[w] = cnt;
    __syncthreads();
    const float total = sred[0] + sred[1] + sred[2] + sred[3];
    const float inv = 1.0f / fmaxf(total, 1.0f);  // bit-exact: match/safe_sum, match in {0,1}

    for (int j = start + t; j < end; j += DIM) scores[j] *= inv;
}

extern "C" void kernel_launch(void* const* d_in, const int* in_sizes, int n_in,
                              void* d_out, int out_size, void* d_ws, size_t ws_size,
                              hipStream_t stream) {
    const float* x     = (const float*)d_in[0];
    const int*   batch = (const int*)d_in[1];

    const int N  = in_sizes[1];          // 1048576
    const int Dd = in_sizes[0] / N;      // 256
    const int G  = (out_size - N) / Dd;  // 2048

    float* emb    = (float*)d_out;
    float* scores = (float*)d_out + (size_t)G * Dd;

    segpool_kernel<<<G, 256, 0, stream>>>(x, batch, emb, scores, N);
}

// Round 3
// 269.433 us; speedup vs baseline: 1.1294x; 1.0934x over previous
//
#include <hip/hip_runtime.h>

// N=1048576 nodes, D=256 feats, G=2048 graphs, batch sorted (int32 on device).
// Out = [graph_embedding (G*256 f32), attention_scores (N f32)].
//
// 3-kernel plan:
//  1) bounds_kernel : bounds[g] = lower_bound(batch, g), bounds[G] = N
//  2) partial_kernel: 4 blocks/graph x 4 waves = 16 wave-slices/graph.
//     Each wave streams a contiguous row run with a 4-deep float4 prefetch
//     ring (4KB in flight), tracking per-column (max, argmax, tie) for its
//     4 owned columns. Pure read stream; partials -> d_ws.
//  3) final_kernel  : per graph, combine 16 partials/column, write emb,
//     mark matches in scores, (rare) tie rescan, count, scale.

constexpr int DIM = 256;
constexpr int WSL = 16;                 // wave-slices per graph
constexpr float NEG_CLAMP = -3.4e38f;

__device__ __forceinline__ int lower_bound_i32(const int* __restrict__ a, int n, int v) {
    int lo = 0, hi = n;
    while (lo < hi) {
        int mid = (lo + hi) >> 1;
        if (a[mid] < v) lo = mid + 1; else hi = mid;
    }
    return lo;
}

__global__ void bounds_kernel(const int* __restrict__ batch, int* __restrict__ bounds,
                              int N, int G) {
    int g = blockIdx.x * blockDim.x + threadIdx.x;
    if (g < G)  bounds[g] = lower_bound_i32(batch, N, g);
    if (g == G) bounds[G] = N;
}

__global__ __launch_bounds__(256, 8)
void partial_kernel(const float* __restrict__ x,
                    const int* __restrict__ bounds,
                    float* __restrict__ pmax,          // [G][WSL][DIM]
                    int* __restrict__ pam,             // [G][WSL][DIM]
                    unsigned int* __restrict__ ptie)   // [G][WSL][64] bitmasks
{
    const int bid = blockIdx.x;          // g*4 + s
    const int g = bid >> 2;
    const int s = bid & 3;
    const int w = threadIdx.x >> 6;
    const int l = threadIdx.x & 63;
    const int wi = s * 4 + w;            // wave-slice 0..15

    const int start = bounds[g];
    const int end   = bounds[g + 1];
    const int len   = end - start;
    const int q     = (len + WSL - 1) / WSL;

    int a = start + wi * q;
    int b = a + q;
    if (a > end) a = end;
    if (b > end) b = end;
    const int n = b - a;

    const float NI = -__builtin_huge_valf();
    float m0 = NI, m1 = NI, m2 = NI, m3 = NI;
    int   a0 = -1, a1 = -1, a2 = -1, a3 = -1;
    unsigned int tieb = 0;

    // row r, lane l -> p[(r-a)*64]
    const float4* __restrict__ p = (const float4*)x + (size_t)a * 64 + l;

#define UPD4(v, idx) do {                                             \
        bool g0 = (v).x > m0, g1 = (v).y > m1,                        \
             g2 = (v).z > m2, g3 = (v).w > m3;                        \
        tieb |= ((v).x == m0) ? 1u : 0u;                              \
        tieb |= ((v).y == m1) ? 2u : 0u;                              \
        tieb |= ((v).z == m2) ? 4u : 0u;                              \
        tieb |= ((v).w == m3) ? 8u : 0u;                              \
        a0 = g0 ? (idx) : a0;  m0 = g0 ? (v).x : m0;                  \
        a1 = g1 ? (idx) : a1;  m1 = g1 ? (v).y : m1;                  \
        a2 = g2 ? (idx) : a2;  m2 = g2 ? (v).z : m2;                  \
        a3 = g3 ? (idx) : a3;  m3 = g3 ? (v).w : m3;                  \
    } while (0)

    // 4-deep prefetch ring, statically indexed (no runtime-indexed arrays)
    float4 f0 = make_float4(NI, NI, NI, NI), f1 = f0, f2 = f0, f3 = f0;
    if (n > 0) f0 = p[0 * 64];
    if (n > 1) f1 = p[1 * 64];
    if (n > 2) f2 = p[2 * 64];
    if (n > 3) f3 = p[3 * 64];

    int k = 0;
    for (; k + 8 <= n; k += 4) {
        UPD4(f0, a + k + 0);  f0 = p[(size_t)(k + 4) * 64];
        UPD4(f1, a + k + 1);  f1 = p[(size_t)(k + 5) * 64];
        UPD4(f2, a + k + 2);  f2 = p[(size_t)(k + 6) * 64];
        UPD4(f3, a + k + 3);  f3 = p[(size_t)(k + 7) * 64];
    }
    const int rem = n - k;   // 0..7
    if (rem > 0) UPD4(f0, a + k + 0);
    if (rem > 1) UPD4(f1, a + k + 1);
    if (rem > 2) UPD4(f2, a + k + 2);
    if (rem > 3) UPD4(f3, a + k + 3);
    for (int r = k + 4; r < n; ++r) {
        float4 v = p[(size_t)r * 64];
        UPD4(v, a + r);
    }
#undef UPD4

    const size_t base = ((size_t)g * WSL + wi) * DIM + (size_t)l * 4;
    *(float4*)(pmax + base) = make_float4(m0, m1, m2, m3);
    *(int4*)(pam + base)    = make_int4(a0, a1, a2, a3);
    ptie[((size_t)g * WSL + wi) * 64 + l] = tieb;   // bits 0..3 = cols 4l..4l+3
}

__global__ __launch_bounds__(256, 8)
void final_kernel(const float* __restrict__ x,
                  const int* __restrict__ bounds,
                  const float* __restrict__ pmax,
                  const int* __restrict__ pam,
                  const unsigned int* __restrict__ ptie,
                  float* __restrict__ emb,
                  float* __restrict__ scores)
{
    const int g = blockIdx.x;
    const int t = threadIdx.x;
    const int start = bounds[g];
    const int end   = bounds[g + 1];

    // zero this graph's scores region
    for (int j = start + t; j < end; j += DIM) scores[j] = 0.0f;

    // combine 16 partials for column t
    const size_t pb = (size_t)g * WSL * DIM + t;
    float pv[WSL];
    #pragma unroll
    for (int i = 0; i < WSL; ++i) pv[i] = pmax[pb + (size_t)i * DIM];

    float M = -__builtin_huge_valf();
    #pragma unroll
    for (int i = 0; i < WSL; ++i) M = fmaxf(M, pv[i]);
    emb[(size_t)g * DIM + t] = fmaxf(M, NEG_CLAMP);

    __syncthreads();   // zeros visible before marking

    bool rescan = false;
    #pragma unroll
    for (int i = 0; i < WSL; ++i) {
        if (pv[i] == M) {
            const int am = pam[pb + (size_t)i * DIM];
            if (am >= 0) scores[am] = 1.0f;      // duplicate 1.0 stores benign
            rescan = rescan ||
                (((ptie[((size_t)g * WSL + i) * 64 + (t >> 2)] >> (t & 3)) & 1u) != 0u);
        }
    }
    if (rescan) {
        // rare: exact duplicate of a slice's running max in a max-attaining
        // slice; re-scan column t, mark every exact hit of the final max.
        const float* __restrict__ col = x + t;
        for (int j = start; j < end; ++j)
            if (col[(size_t)j * DIM] == M) scores[j] = 1.0f;
    }
    __syncthreads();   // all 1-writes visible before counting

    float cnt = 0.0f;
    for (int j = start + t; j < end; j += DIM) cnt += scores[j];
    for (int off = 32; off > 0; off >>= 1) cnt += __shfl_down(cnt, off, 64);

    __shared__ float sred[4];
    const int w = t >> 6, l = t & 63;
    if (l == 0) sred[w] = cnt;
    __syncthreads();
    const float total = sred[0] + sred[1] + sred[2] + sred[3];
    const float inv = 1.0f / fmaxf(total, 1.0f);  // exact: numerator is 0 or 1

    for (int j = start + t; j < end; j += DIM) scores[j] *= inv;
}

extern "C" void kernel_launch(void* const* d_in, const int* in_sizes, int n_in,
                              void* d_out, int out_size, void* d_ws, size_t ws_size,
                              hipStream_t stream) {
    const float* x     = (const float*)d_in[0];
    const int*   batch = (const int*)d_in[1];

    const int N  = in_sizes[1];          // 1048576
    const int Dd = in_sizes[0] / N;      // 256
    const int G  = (out_size - N) / Dd;  // 2048

    float* emb    = (float*)d_out;
    float* scores = (float*)d_out + (size_t)G * Dd;

    // workspace layout (≈75 MB; ws is ~4 GB)
    char* ws = (char*)d_ws;
    int* bounds = (int*)ws;
    size_t off = (((size_t)(G + 1) * sizeof(int)) + 1023) & ~(size_t)1023;
    float* pmax = (float*)(ws + off);  off += (size_t)G * WSL * DIM * sizeof(float);
    int*   pam  = (int*)(ws + off);    off += (size_t)G * WSL * DIM * sizeof(int);
    unsigned int* ptie = (unsigned int*)(ws + off);

    bounds_kernel<<<(G + 256) / 256, 256, 0, stream>>>(batch, bounds, N, G);
    partial_kernel<<<G * 4, 256, 0, stream>>>(x, bounds, pmax, pam, ptie);
    final_kernel<<<G, 256, 0, stream>>>(x, bounds, pmax, pam, ptie, emb, scores);
}